// Round 6
// baseline (654.741 us; speedup 1.0000x reference)
//
#include <hip/hip_runtime.h>
#include <hip/hip_bf16.h>

#define BATCH 8
#define CDIM 192
#define HEADS 8
#define CH 24
#define HH 128
#define WW 128
#define NPIX (HH*WW)                  // 16384
#define NELEM (BATCH*CDIM*NPIX)       // 25165824
#define NP4 (NPIX/4)                  // 4096

#define NSLAB 32
#define NJOBS 624                     // 576 cross dots + 24 q self + 24 k self

typedef __attribute__((ext_vector_type(8))) short bf16x8;
typedef __attribute__((ext_vector_type(4))) float f32x4;

// ---------------------------------------------------------------------------
// Static pool: t0q,t0k,t0v,q,k,v (fp32, 96 MiB each) + misc tail.
// ---------------------------------------------------------------------------
#define UNIT 100663296ull
__device__ __align__(256) unsigned char g_pool[6 * UNIT + (16u << 20)];

#define OFF_T0Q  (0 * UNIT)
#define OFF_T0K  (1 * UNIT)
#define OFF_T0V  (2 * UNIT)
#define OFF_Q    (3 * UNIT)
#define OFF_K    (4 * UNIT)
#define OFF_V    (5 * UNIT)
#define OFF_MISC (6 * UNIT)
#define OFF_PART (OFF_MISC)                            // 64*32*624*4 = 5111808
#define OFF_S    (OFF_MISC + 5111808ull)               // 64*624*4   = 159744
#define OFF_M    (OFF_S + 159744ull)                   // 8*192*192*4 = 1179648
#define OFF_MF   (OFF_M + 1179648ull)                  // hi+lo bf16  = 1179648

// round-to-nearest-even fp32 -> bf16 (bit pattern)
__device__ inline unsigned short bf_rne(float x) {
  unsigned u = __float_as_uint(x);
  unsigned r = (u + 0x7fffu + ((u >> 16) & 1u)) >> 16;
  return (unsigned short)r;
}
__device__ inline void f32_split(float x, unsigned short& h, unsigned short& l) {
  h = bf_rne(x);
  float hf = __uint_as_float(((unsigned)h) << 16);
  l = bf_rne(x - hf);
}

// ---------------------------------------------------------------------------
// Weight/M -> A-fragment layout (hi at base, lo at +nb*CDIM*CDIM elems).
// F_hi[(((b*12+mf)*6+ks)*64+lane)*8+j] = bf16_hi(W[b][mf*16+(lane&15)]
//                                                [ks*32+(lane>>4)*8+j])
// ---------------------------------------------------------------------------
__global__ __launch_bounds__(64) void w_to_frag(const float* __restrict__ W,
                                                unsigned short* __restrict__ F,
                                                int nb) {
  const int b = blockIdx.x / 12, mf = blockIdx.x % 12;
  const int lane = threadIdx.x;
  const int row = mf * 16 + (lane & 15);
  const size_t lo = (size_t)nb * CDIM * CDIM;
#pragma unroll
  for (int ks = 0; ks < 6; ++ks) {
    const int k0 = ks * 32 + (lane >> 4) * 8;
    const float* src = W + ((size_t)b * CDIM + row) * CDIM + k0;
    bf16x8 hv, lv;
#pragma unroll
    for (int j = 0; j < 8; ++j) {
      unsigned short h, l;
      f32_split(src[j], h, l);
      hv[j] = (short)h;
      lv[j] = (short)l;
    }
    const size_t didx = (((size_t)(blockIdx.x) * 6 + ks) * 64 + lane) * 8;
    *(bf16x8*)(F + didx) = hv;
    *(bf16x8*)(F + lo + didx) = lv;
  }
}

// ---------------------------------------------------------------------------
// MFMA GEMM reading fp32 activations directly; split-bf16 AhBh+AhBl+AlBh.
// NT=1: Out0 = W0 @ X.  NT=2: Out0 = W0 @ X, Out1 = W1 @ X (shared B loads
// and conversion; MFMA is cheap at 14% util).
// Per K-tile: register-prefetch next tile (hides HBM latency), stage fp32
// [32][132] in LDS with XOR-swizzled columns (kills 4-way bank conflict on
// the column-walk conversion reads), per-lane hi/lo split, MFMA.
// ---------------------------------------------------------------------------
template <int NT>
__global__ __launch_bounds__(256) void mfma_gemm_nt(
    const float* __restrict__ X,
    const unsigned short* __restrict__ WF0,
    const unsigned short* __restrict__ WF1,
    size_t w_lo, int w_bstride,
    float* __restrict__ Out0, float* __restrict__ Out1) {
  const int bn = blockIdx.x;  // 0..127 pixel tile
  const int bm = blockIdx.y;  // 0..2 M tile
  const int b = blockIdx.z;
  const int t = threadIdx.x;
  const int lane = t & 63, wid = t >> 6;
  const int wm = wid >> 1, wn = wid & 1;
  const int kq = lane >> 4;

  __shared__ float Xs[32][132];

  const size_t wbase = (size_t)b * w_bstride;
  const float* Xb = X + (size_t)b * CDIM * NPIX;
  const int col4 = (t & 31) * 4;
  const int r0 = t >> 5;
  const int pxl = wn * 64 + (lane & 15);

  f32x4 acc0[2][4];
  f32x4 acc1[2][4];
#pragma unroll
  for (int mi = 0; mi < 2; ++mi)
#pragma unroll
    for (int ni = 0; ni < 4; ++ni) {
      acc0[mi][ni] = (f32x4){0.f, 0.f, 0.f, 0.f};
      if constexpr (NT == 2) acc1[mi][ni] = (f32x4){0.f, 0.f, 0.f, 0.f};
    }

  // prefetch K-tile 0
  float4 pre[4];
#pragma unroll
  for (int p = 0; p < 4; ++p)
    pre[p] = *(const float4*)(Xb + (size_t)(r0 + 8 * p) * NPIX + bn * 128 + col4);

#pragma unroll
  for (int ks = 0; ks < 6; ++ks) {
    if (ks) __syncthreads();   // all waves done reading Xs of previous tile
    // store staged registers (rows r=r0+8p; swizzle col by (r>>3)&3 = p)
#pragma unroll
    for (int p = 0; p < 4; ++p)
      *(float4*)&Xs[r0 + 8 * p][col4 ^ ((p & 3) << 2)] = pre[p];
    // issue next tile's loads; latency hides under convert+MFMA below
    if (ks < 5) {
#pragma unroll
      for (int p = 0; p < 4; ++p)
        pre[p] = *(const float4*)(Xb + (size_t)((ks + 1) * 32 + r0 + 8 * p) * NPIX +
                                  bn * 128 + col4);
    }
    __syncthreads();

    // A-fragments for this K-tile (tiny, L2-served)
    bf16x8 Ah0[2], Al0[2], Ah1[2], Al1[2];
#pragma unroll
    for (int mi = 0; mi < 2; ++mi) {
      const int mf = bm * 4 + wm * 2 + mi;
      const size_t idx = wbase + (((size_t)(mf * 6 + ks)) * 64 + lane) * 8;
      Ah0[mi] = *(const bf16x8*)(WF0 + idx);
      Al0[mi] = *(const bf16x8*)(WF0 + w_lo + idx);
      if constexpr (NT == 2) {
        Ah1[mi] = *(const bf16x8*)(WF1 + idx);
        Al1[mi] = *(const bf16x8*)(WF1 + w_lo + idx);
      }
    }

    // per-lane conversion to B fragments (swizzled column read)
    bf16x8 Bh[4], Bl[4];
#pragma unroll
    for (int ni = 0; ni < 4; ++ni) {
      const int pxs = (pxl + ni * 16) ^ (kq << 2);
#pragma unroll
      for (int j = 0; j < 8; ++j) {
        unsigned short h, l;
        f32_split(Xs[kq * 8 + j][pxs], h, l);
        Bh[ni][j] = (short)h;
        Bl[ni][j] = (short)l;
      }
    }

#pragma unroll
    for (int mi = 0; mi < 2; ++mi)
#pragma unroll
      for (int ni = 0; ni < 4; ++ni) {
        acc0[mi][ni] = __builtin_amdgcn_mfma_f32_16x16x32_bf16(
            Ah0[mi], Bh[ni], acc0[mi][ni], 0, 0, 0);
        acc0[mi][ni] = __builtin_amdgcn_mfma_f32_16x16x32_bf16(
            Ah0[mi], Bl[ni], acc0[mi][ni], 0, 0, 0);
        acc0[mi][ni] = __builtin_amdgcn_mfma_f32_16x16x32_bf16(
            Al0[mi], Bh[ni], acc0[mi][ni], 0, 0, 0);
        if constexpr (NT == 2) {
          acc1[mi][ni] = __builtin_amdgcn_mfma_f32_16x16x32_bf16(
              Ah1[mi], Bh[ni], acc1[mi][ni], 0, 0, 0);
          acc1[mi][ni] = __builtin_amdgcn_mfma_f32_16x16x32_bf16(
              Ah1[mi], Bl[ni], acc1[mi][ni], 0, 0, 0);
          acc1[mi][ni] = __builtin_amdgcn_mfma_f32_16x16x32_bf16(
              Al1[mi], Bh[ni], acc1[mi][ni], 0, 0, 0);
        }
      }
  }

  // C/D layout: col = lane&15 (pixel), row = (lane>>4)*4 + reg (och)
  const int ocol = bn * 128 + wn * 64 + (lane & 15);
  const int orow = bm * 64 + wm * 32 + (lane >> 4) * 4;
#pragma unroll
  for (int mi = 0; mi < 2; ++mi)
#pragma unroll
    for (int r = 0; r < 4; ++r) {
      const int och = orow + mi * 16 + r;
      float* dst0 = Out0 + ((size_t)b * CDIM + och) * NPIX + ocol;
#pragma unroll
      for (int ni = 0; ni < 4; ++ni) dst0[ni * 16] = acc0[mi][ni][r];
      if constexpr (NT == 2) {
        float* dst1 = Out1 + ((size_t)b * CDIM + och) * NPIX + ocol;
#pragma unroll
        for (int ni = 0; ni < 4; ++ni) dst1[ni * 16] = acc1[mi][ni][r];
      }
    }
}

// ---------------------------------------------------------------------------
// Depthwise 3x3 conv, zero pad (fp32 in/out, channel-major).
// ---------------------------------------------------------------------------
__global__ __launch_bounds__(256) void dwconv(const float* __restrict__ In,
                                              const float* __restrict__ Wd,
                                              float* __restrict__ Out) {
  const int idx = blockIdx.x * 256 + threadIdx.x;
  if (idx >= NELEM / 4) return;
  const int x4 = (idx & 31) * 4;
  const int y = (idx >> 5) & 127;
  const int c = (idx >> 12) % CDIM;
  const int b = idx / (32 * 128 * CDIM);

  const float* base = In + (size_t)(b * CDIM + c) * NPIX;
  float w[9];
#pragma unroll
  for (int i = 0; i < 9; ++i) w[i] = Wd[c * 9 + i];

  float acc0 = 0.f, acc1 = 0.f, acc2 = 0.f, acc3 = 0.f;
#pragma unroll
  for (int dy = 0; dy < 3; ++dy) {
    const int yy = y + dy - 1;
    if (yy < 0 || yy > 127) continue;
    const float* row = base + yy * WW;
    float vb0 = (x4 > 0) ? row[x4 - 1] : 0.f;
    const float4 m = *(const float4*)(row + x4);
    const float vb5 = (x4 + 4 < WW) ? row[x4 + 4] : 0.f;
    const float w0 = w[dy * 3 + 0], w1 = w[dy * 3 + 1], w2 = w[dy * 3 + 2];
    acc0 += w0 * vb0 + w1 * m.x + w2 * m.y;
    acc1 += w0 * m.x + w1 * m.y + w2 * m.z;
    acc2 += w0 * m.y + w1 * m.z + w2 * m.w;
    acc3 += w0 * m.z + w1 * m.w + w2 * vb5;
  }
  float4 o;
  o.x = acc0; o.y = acc1; o.z = acc2; o.w = acc3;
  *(float4*)(Out + (size_t)idx * 4) = o;
}

// ---------------------------------------------------------------------------
// Gram dots: register outer-product, no LDS.
// ---------------------------------------------------------------------------
__global__ __launch_bounds__(256) void dots_partial(const float* __restrict__ Q,
                                                    const float* __restrict__ K,
                                                    float* __restrict__ Part) {
  const int bh = blockIdx.x;
  const int slab = blockIdx.y;
  const int b = bh >> 3, h = bh & 7;
  const int t = threadIdx.x;
  const int pg = t & 15;
  const int sb = t >> 4;
  const int sr = sb >> 2, sc = sb & 3;
  const bool diag = (sr == sc);

  const float4* qb = (const float4*)(Q + (size_t)(b * CDIM + h * CH) * NPIX);
  const float4* kb = (const float4*)(K + (size_t)(b * CDIM + h * CH) * NPIX);
  const int F_PER_SLAB = NP4 / NSLAB;       // 128
  const int NITER = F_PER_SLAB / 16;        // 8

  float acc[6][6];
#pragma unroll
  for (int j = 0; j < 6; ++j)
#pragma unroll
    for (int c = 0; c < 6; ++c) acc[j][c] = 0.f;
  float qq[6] = {0, 0, 0, 0, 0, 0};
  float kk[6] = {0, 0, 0, 0, 0, 0};

  const int f0 = slab * F_PER_SLAB + pg;
  for (int i = 0; i < NITER; ++i) {
    const int f = f0 + 16 * i;
    float4 qv[6], kv[6];
#pragma unroll
    for (int j = 0; j < 6; ++j) qv[j] = qb[(size_t)(sr * 6 + j) * NP4 + f];
#pragma unroll
    for (int j = 0; j < 6; ++j) kv[j] = kb[(size_t)(sc * 6 + j) * NP4 + f];
#pragma unroll
    for (int j = 0; j < 6; ++j)
#pragma unroll
      for (int c = 0; c < 6; ++c)
        acc[j][c] += qv[j].x * kv[c].x + qv[j].y * kv[c].y +
                     qv[j].z * kv[c].z + qv[j].w * kv[c].w;
    if (diag) {
#pragma unroll
      for (int j = 0; j < 6; ++j) {
        qq[j] += qv[j].x * qv[j].x + qv[j].y * qv[j].y + qv[j].z * qv[j].z +
                 qv[j].w * qv[j].w;
        kk[j] += kv[j].x * kv[j].x + kv[j].y * kv[j].y + kv[j].z * kv[j].z +
                 kv[j].w * kv[j].w;
      }
    }
  }

#pragma unroll
  for (int j = 0; j < 6; ++j)
#pragma unroll
    for (int c = 0; c < 6; ++c) {
      float v = acc[j][c];
      v += __shfl_xor(v, 1);
      v += __shfl_xor(v, 2);
      v += __shfl_xor(v, 4);
      v += __shfl_xor(v, 8);
      acc[j][c] = v;
    }
#pragma unroll
  for (int j = 0; j < 6; ++j) {
    float a = qq[j], bb = kk[j];
    a += __shfl_xor(a, 1); a += __shfl_xor(a, 2);
    a += __shfl_xor(a, 4); a += __shfl_xor(a, 8);
    bb += __shfl_xor(bb, 1); bb += __shfl_xor(bb, 2);
    bb += __shfl_xor(bb, 4); bb += __shfl_xor(bb, 8);
    qq[j] = a; kk[j] = bb;
  }

  if (pg == 0) {
    float* P = Part + ((size_t)bh * NSLAB + slab) * NJOBS;
#pragma unroll
    for (int j = 0; j < 6; ++j)
#pragma unroll
      for (int c = 0; c < 6; ++c)
        P[(sr * 6 + j) * 24 + sc * 6 + c] = acc[j][c];
    if (diag) {
#pragma unroll
      for (int j = 0; j < 6; ++j) {
        P[576 + sr * 6 + j] = qq[j];
        P[600 + sc * 6 + j] = kk[j];
      }
    }
  }
}

__global__ __launch_bounds__(640) void dots_reduce(const float* __restrict__ Part,
                                                   float* __restrict__ S) {
  const int bh = blockIdx.x;
  const int job = threadIdx.x;
  if (job >= NJOBS) return;
  float s = 0.f;
  for (int i = 0; i < NSLAB; ++i)
    s += Part[((size_t)bh * NSLAB + i) * NJOBS + job];
  S[bh * NJOBS + job] = s;
}

// ---------------------------------------------------------------------------
// Normalize, softmax, fold proj: M_b = proj_w @ blockdiag(attn_b).
// ---------------------------------------------------------------------------
__global__ __launch_bounds__(576) void build_M(const float* __restrict__ S,
                                               const float* __restrict__ PW,
                                               const float* __restrict__ Temp,
                                               float* __restrict__ M) {
  const int b = blockIdx.x, h = blockIdx.y;
  const int bh = b * 8 + h;
  __shared__ float att[CH][CH];
  __shared__ float qn[CH], kn[CH];
  const int t = threadIdx.x;
  const float* Sb = S + (size_t)bh * NJOBS;

  if (t < CH) {
    qn[t] = fmaxf(sqrtf(Sb[576 + t]), 1e-12f);
    kn[t] = fmaxf(sqrtf(Sb[600 + t]), 1e-12f);
  }
  __syncthreads();
  const float temp = Temp[h];
  if (t < 576) {
    const int c = t / 24, d = t % 24;
    att[c][d] = Sb[t] / (qn[c] * kn[d]) * temp;
  }
  __syncthreads();
  if (t < CH) {
    float mx = -1e30f;
    for (int d = 0; d < CH; ++d) mx = fmaxf(mx, att[t][d]);
    float sum = 0.f;
    for (int d = 0; d < CH; ++d) {
      const float e = __expf(att[t][d] - mx);
      att[t][d] = e;
      sum += e;
    }
    const float inv = 1.f / sum;
    for (int d = 0; d < CH; ++d) att[t][d] *= inv;
  }
  __syncthreads();
  for (int i = t; i < CDIM * CH; i += 576) {
    const int o = i / CH, d = i % CH;
    float s = 0.f;
#pragma unroll
    for (int c = 0; c < CH; ++c) s += PW[o * CDIM + h * CH + c] * att[c][d];
    M[((size_t)b * CDIM + o) * CDIM + h * CH + d] = s;
  }
}

// ---------------------------------------------------------------------------

extern "C" void kernel_launch(void* const* d_in, const int* in_sizes, int n_in,
                              void* d_out, int out_size, void* d_ws, size_t ws_size,
                              hipStream_t stream) {
  const float* x_feat = (const float*)d_in[0];
  const float* y_feat = (const float*)d_in[1];
  const float* q_pw   = (const float*)d_in[2];
  const float* q_dw   = (const float*)d_in[3];
  const float* k_pw   = (const float*)d_in[4];
  const float* k_dw   = (const float*)d_in[5];
  const float* v_pw   = (const float*)d_in[6];
  const float* v_dw   = (const float*)d_in[7];
  const float* proj_w = (const float*)d_in[8];
  const float* temp   = (const float*)d_in[9];
  float* out = (float*)d_out;

  unsigned char* pool;
  hipGetSymbolAddress((void**)&pool, HIP_SYMBOL(g_pool));
  float* t0q = (float*)(pool + OFF_T0Q);
  float* t0k = (float*)(pool + OFF_T0K);
  float* t0v = (float*)(pool + OFF_T0V);
  float* q  = (float*)(pool + OFF_Q);
  float* k  = (float*)(pool + OFF_K);
  float* v  = (float*)(pool + OFF_V);
  float* part = (float*)(pool + OFF_PART);
  float* S    = (float*)(pool + OFF_S);
  float* M    = (float*)(pool + OFF_M);
  unsigned short* MF = (unsigned short*)(pool + OFF_MF);

  unsigned short* WQF = MF + 2ull * 8 * CDIM * CDIM;
  unsigned short* WKF = WQF + 2ull * CDIM * CDIM;
  unsigned short* WVF = WKF + 2ull * CDIM * CDIM;

  const size_t w1_lo = (size_t)1 * CDIM * CDIM;
  const size_t w8_lo = (size_t)8 * CDIM * CDIM;

  const dim3 ggrid(NPIX / 128, 3, BATCH);
  const int dwgrid = (NELEM / 4) / 256;

  // weight conversions (tiny)
  w_to_frag<<<12, 64, 0, stream>>>(q_pw, WQF, 1);
  w_to_frag<<<12, 64, 0, stream>>>(k_pw, WKF, 1);
  w_to_frag<<<12, 64, 0, stream>>>(v_pw, WVF, 1);

  // t0q = q_pw @ x; {t0k,t0v} = {k_pw,v_pw} @ y (shared y read/conversion)
  mfma_gemm_nt<1><<<ggrid, 256, 0, stream>>>(x_feat, WQF, nullptr, w1_lo, 0,
                                             t0q, nullptr);
  mfma_gemm_nt<2><<<ggrid, 256, 0, stream>>>(y_feat, WKF, WVF, w1_lo, 0,
                                             t0k, t0v);

  // depthwise convs
  dwconv<<<dwgrid, 256, 0, stream>>>(t0q, q_dw, q);
  dwconv<<<dwgrid, 256, 0, stream>>>(t0k, k_dw, k);
  dwconv<<<dwgrid, 256, 0, stream>>>(t0v, v_dw, v);

  // attention gram + softmax + proj fold
  dots_partial<<<dim3(64, NSLAB), 256, 0, stream>>>(q, k, part);
  dots_reduce<<<64, 640, 0, stream>>>(part, S);
  build_M<<<dim3(BATCH, HEADS), 576, 0, stream>>>(S, proj_w, temp, M);
  w_to_frag<<<8 * 12, 64, 0, stream>>>(M, MF, 8);

  // out = M_b @ v (reads fp32 v directly)
  mfma_gemm_nt<1><<<ggrid, 256, 0, stream>>>(v, MF, nullptr, w8_lo,
                                             CDIM * CDIM, out, nullptr);
}

// Round 8
// 433.667 us; speedup vs baseline: 1.5098x; 1.5098x over previous
//
#include <hip/hip_runtime.h>
#include <hip/hip_bf16.h>

#define BATCH 8
#define CDIM 192
#define HEADS 8
#define CH 24
#define HH 128
#define WW 128
#define NPIX (HH*WW)                  // 16384
#define NELEM (BATCH*CDIM*NPIX)       // 25165824
#define NP4 (NPIX/4)                  // 4096

#define NSLAB 32
#define NJOBS 624                     // 576 cross dots + 24 q self + 24 k self

typedef __attribute__((ext_vector_type(8))) short bf16x8;
typedef __attribute__((ext_vector_type(4))) float f32x4;
typedef __attribute__((ext_vector_type(4))) unsigned int u32x4;

// ---------------------------------------------------------------------------
// Static pool: t0, q, k, v (fp32, 96 MiB each) + misc tail.
// ---------------------------------------------------------------------------
#define UNIT 100663296ull
__device__ __align__(256) unsigned char g_pool[4 * UNIT + (16u << 20)];

#define OFF_T0   (0 * UNIT)
#define OFF_Q    (1 * UNIT)
#define OFF_K    (2 * UNIT)
#define OFF_V    (3 * UNIT)
#define OFF_MISC (4 * UNIT)
#define OFF_PART (OFF_MISC)                            // 64*32*624*4 = 5111808
#define OFF_S    (OFF_MISC + 5111808ull)               // 64*624*4   = 159744
#define OFF_M    (OFF_S + 159744ull)                   // 8*192*192*4 = 1179648
#define OFF_MF   (OFF_M + 1179648ull)                  // hi+lo bf16  = 1179648

// round-to-nearest-even fp32 -> bf16 (bit pattern)
__device__ inline unsigned short bf_rne(float x) {
  unsigned u = __float_as_uint(x);
  unsigned r = (u + 0x7fffu + ((u >> 16) & 1u)) >> 16;
  return (unsigned short)r;
}
__device__ inline void f32_split(float x, unsigned short& h, unsigned short& l) {
  h = bf_rne(x);
  float hf = __uint_as_float(((unsigned)h) << 16);
  l = bf_rne(x - hf);
}

// ---------------------------------------------------------------------------
// Weight/M -> A-fragment layout (hi at base, lo at +nb*CDIM*CDIM elems).
// F_hi[(((b*12+mf)*6+ks)*64+lane)*8+j] = bf16_hi(W[b][mf*16+(lane&15)]
//                                                [ks*32+(lane>>4)*8+j])
// ---------------------------------------------------------------------------
__global__ __launch_bounds__(64) void w_to_frag(const float* __restrict__ W,
                                                unsigned short* __restrict__ F,
                                                int nb) {
  const int b = blockIdx.x / 12, mf = blockIdx.x % 12;
  const int lane = threadIdx.x;
  const int row = mf * 16 + (lane & 15);
  const size_t lo = (size_t)nb * CDIM * CDIM;
#pragma unroll
  for (int ks = 0; ks < 6; ++ks) {
    const int k0 = ks * 32 + (lane >> 4) * 8;
    const float* src = W + ((size_t)b * CDIM + row) * CDIM + k0;
    bf16x8 hv, lv;
#pragma unroll
    for (int j = 0; j < 8; ++j) {
      unsigned short h, l;
      f32_split(src[j], h, l);
      hv[j] = (short)h;
      lv[j] = (short)l;
    }
    const size_t didx = (((size_t)(blockIdx.x) * 6 + ks) * 64 + lane) * 8;
    *(bf16x8*)(F + didx) = hv;
    *(bf16x8*)(F + lo + didx) = lv;
  }
}

// ---------------------------------------------------------------------------
// MFMA GEMM, M=192 per block (whole channel dim), fp32 B staged in LDS.
// Split-bf16: B hi = bit-truncation, lo = rne(residual); A rne hi/lo.
// acc += Ah*Bh + Ah*Bl + Al*Bh.
// Waves (wm,wn) 2x2: wave owns M rows wm*96..+95 (6 frags), px wn*64..+63.
// LDS swizzle: col ^ ((row>>3 & 1) << 4) -> conversion reads 2-way (free).
// Grid (128 px-tiles, 8 batches). launch_bounds(256,2) caps VGPR at 256.
// ---------------------------------------------------------------------------
__global__ __launch_bounds__(256, 2) void mfma_gemm192(
    const float* __restrict__ X,
    const unsigned short* __restrict__ WF, size_t w_lo,
    int w_bstride,
    float* __restrict__ Out) {
  const int bn = blockIdx.x;  // 0..127 pixel tile (one image row)
  const int b = blockIdx.y;
  const int t = threadIdx.x;
  const int lane = t & 63, wid = t >> 6;
  const int wm = wid >> 1, wn = wid & 1;
  const int kq = lane >> 4;

  __shared__ float Xs[32][132];

  const size_t wbase = (size_t)b * w_bstride;
  const float* Xb = X + (size_t)b * CDIM * NPIX;
  const int col4 = (t & 31) * 4;
  const int r0 = t >> 5;
  const int pxl = wn * 64 + (lane & 15);

  f32x4 acc[6][4];
#pragma unroll
  for (int mi = 0; mi < 6; ++mi)
#pragma unroll
    for (int ni = 0; ni < 4; ++ni) acc[mi][ni] = (f32x4){0.f, 0.f, 0.f, 0.f};

  for (int ks = 0; ks < 6; ++ks) {
    // stage B tile 32x128 fp32 into LDS (swizzled column halves)
    float4 st[4];
#pragma unroll
    for (int p = 0; p < 4; ++p)
      st[p] = *(const float4*)(Xb + (size_t)(ks * 32 + r0 + 8 * p) * NPIX +
                               bn * 128 + col4);
#pragma unroll
    for (int p = 0; p < 4; ++p)
      *(float4*)&Xs[r0 + 8 * p][col4 ^ ((p & 1) << 4)] = st[p];
    __syncthreads();

    // A-fragments for this K-tile (tiny, L2-served)
    bf16x8 Ah[6], Al[6];
#pragma unroll
    for (int mi = 0; mi < 6; ++mi) {
      const int mf = wm * 6 + mi;
      const size_t idx = wbase + (((size_t)(mf * 6 + ks)) * 64 + lane) * 8;
      Ah[mi] = *(const bf16x8*)(WF + idx);
      Al[mi] = *(const bf16x8*)(WF + w_lo + idx);
    }

    // per-lane B conversion: hi = truncate, lo = rne(residual), pair-packed
    u32x4 Bh[4], Bl[4];
#pragma unroll
    for (int ni = 0; ni < 4; ++ni) {
      const int pxs = (pxl + ni * 16) ^ ((kq & 1) << 4);
#pragma unroll
      for (int jp = 0; jp < 4; ++jp) {
        const float x0 = Xs[kq * 8 + 2 * jp][pxs];
        const float x1 = Xs[kq * 8 + 2 * jp + 1][pxs];
        const unsigned u0 = __float_as_uint(x0);
        const unsigned u1 = __float_as_uint(x1);
        Bh[ni][jp] = (u1 & 0xffff0000u) | (u0 >> 16);
        const float rr0 = x0 - __uint_as_float(u0 & 0xffff0000u);
        const float rr1 = x1 - __uint_as_float(u1 & 0xffff0000u);
        Bl[ni][jp] = ((unsigned)bf_rne(rr1) << 16) | (unsigned)bf_rne(rr0);
      }
    }
    __syncthreads();

#pragma unroll
    for (int mi = 0; mi < 6; ++mi)
#pragma unroll
      for (int ni = 0; ni < 4; ++ni) {
        const bf16x8 bh = __builtin_bit_cast(bf16x8, Bh[ni]);
        const bf16x8 bl = __builtin_bit_cast(bf16x8, Bl[ni]);
        acc[mi][ni] = __builtin_amdgcn_mfma_f32_16x16x32_bf16(
            Ah[mi], bh, acc[mi][ni], 0, 0, 0);
        acc[mi][ni] = __builtin_amdgcn_mfma_f32_16x16x32_bf16(
            Ah[mi], bl, acc[mi][ni], 0, 0, 0);
        acc[mi][ni] = __builtin_amdgcn_mfma_f32_16x16x32_bf16(
            Al[mi], bh, acc[mi][ni], 0, 0, 0);
      }
  }

  // C/D layout: col = lane&15 (pixel), row = (lane>>4)*4 + reg (och)
  const int ocol = bn * 128 + wn * 64 + (lane & 15);
  const int orow = wm * 96 + (lane >> 4) * 4;
#pragma unroll
  for (int mi = 0; mi < 6; ++mi)
#pragma unroll
    for (int r = 0; r < 4; ++r) {
      const int och = orow + mi * 16 + r;
      float* dst = Out + ((size_t)b * CDIM + och) * NPIX + ocol;
#pragma unroll
      for (int ni = 0; ni < 4; ++ni) dst[ni * 16] = acc[mi][ni][r];
    }
}

// ---------------------------------------------------------------------------
// Depthwise 3x3 conv, zero pad (fp32 in/out, channel-major).
// ---------------------------------------------------------------------------
__global__ __launch_bounds__(256) void dwconv(const float* __restrict__ In,
                                              const float* __restrict__ Wd,
                                              float* __restrict__ Out) {
  const int idx = blockIdx.x * 256 + threadIdx.x;
  if (idx >= NELEM / 4) return;
  const int x4 = (idx & 31) * 4;
  const int y = (idx >> 5) & 127;
  const int c = (idx >> 12) % CDIM;
  const int b = idx / (32 * 128 * CDIM);

  const float* base = In + (size_t)(b * CDIM + c) * NPIX;
  float w[9];
#pragma unroll
  for (int i = 0; i < 9; ++i) w[i] = Wd[c * 9 + i];

  float acc0 = 0.f, acc1 = 0.f, acc2 = 0.f, acc3 = 0.f;
#pragma unroll
  for (int dy = 0; dy < 3; ++dy) {
    const int yy = y + dy - 1;
    if (yy < 0 || yy > 127) continue;
    const float* row = base + yy * WW;
    float vb0 = (x4 > 0) ? row[x4 - 1] : 0.f;
    const float4 m = *(const float4*)(row + x4);
    const float vb5 = (x4 + 4 < WW) ? row[x4 + 4] : 0.f;
    const float w0 = w[dy * 3 + 0], w1 = w[dy * 3 + 1], w2 = w[dy * 3 + 2];
    acc0 += w0 * vb0 + w1 * m.x + w2 * m.y;
    acc1 += w0 * m.x + w1 * m.y + w2 * m.z;
    acc2 += w0 * m.y + w1 * m.z + w2 * m.w;
    acc3 += w0 * m.z + w1 * m.w + w2 * vb5;
  }
  float4 o;
  o.x = acc0; o.y = acc1; o.z = acc2; o.w = acc3;
  *(float4*)(Out + (size_t)idx * 4) = o;
}

// ---------------------------------------------------------------------------
// Gram dots: register outer-product, no LDS.
// ---------------------------------------------------------------------------
__global__ __launch_bounds__(256) void dots_partial(const float* __restrict__ Q,
                                                    const float* __restrict__ K,
                                                    float* __restrict__ Part) {
  const int bh = blockIdx.x;
  const int slab = blockIdx.y;
  const int b = bh >> 3, h = bh & 7;
  const int t = threadIdx.x;
  const int pg = t & 15;
  const int sb = t >> 4;
  const int sr = sb >> 2, sc = sb & 3;
  const bool diag = (sr == sc);

  const float4* qb = (const float4*)(Q + (size_t)(b * CDIM + h * CH) * NPIX);
  const float4* kb = (const float4*)(K + (size_t)(b * CDIM + h * CH) * NPIX);
  const int F_PER_SLAB = NP4 / NSLAB;       // 128
  const int NITER = F_PER_SLAB / 16;        // 8

  float acc[6][6];
#pragma unroll
  for (int j = 0; j < 6; ++j)
#pragma unroll
    for (int c = 0; c < 6; ++c) acc[j][c] = 0.f;
  float qq[6] = {0, 0, 0, 0, 0, 0};
  float kk[6] = {0, 0, 0, 0, 0, 0};

  const int f0 = slab * F_PER_SLAB + pg;
  for (int i = 0; i < NITER; ++i) {
    const int f = f0 + 16 * i;
    float4 qv[6], kv[6];
#pragma unroll
    for (int j = 0; j < 6; ++j) qv[j] = qb[(size_t)(sr * 6 + j) * NP4 + f];
#pragma unroll
    for (int j = 0; j < 6; ++j) kv[j] = kb[(size_t)(sc * 6 + j) * NP4 + f];
#pragma unroll
    for (int j = 0; j < 6; ++j)
#pragma unroll
      for (int c = 0; c < 6; ++c)
        acc[j][c] += qv[j].x * kv[c].x + qv[j].y * kv[c].y +
                     qv[j].z * kv[c].z + qv[j].w * kv[c].w;
    if (diag) {
#pragma unroll
      for (int j = 0; j < 6; ++j) {
        qq[j] += qv[j].x * qv[j].x + qv[j].y * qv[j].y + qv[j].z * qv[j].z +
                 qv[j].w * qv[j].w;
        kk[j] += kv[j].x * kv[j].x + kv[j].y * kv[j].y + kv[j].z * kv[j].z +
                 kv[j].w * kv[j].w;
      }
    }
  }

#pragma unroll
  for (int j = 0; j < 6; ++j)
#pragma unroll
    for (int c = 0; c < 6; ++c) {
      float v = acc[j][c];
      v += __shfl_xor(v, 1);
      v += __shfl_xor(v, 2);
      v += __shfl_xor(v, 4);
      v += __shfl_xor(v, 8);
      acc[j][c] = v;
    }
#pragma unroll
  for (int j = 0; j < 6; ++j) {
    float a = qq[j], bb = kk[j];
    a += __shfl_xor(a, 1); a += __shfl_xor(a, 2);
    a += __shfl_xor(a, 4); a += __shfl_xor(a, 8);
    bb += __shfl_xor(bb, 1); bb += __shfl_xor(bb, 2);
    bb += __shfl_xor(bb, 4); bb += __shfl_xor(bb, 8);
    qq[j] = a; kk[j] = bb;
  }

  if (pg == 0) {
    float* P = Part + ((size_t)bh * NSLAB + slab) * NJOBS;
#pragma unroll
    for (int j = 0; j < 6; ++j)
#pragma unroll
      for (int c = 0; c < 6; ++c)
        P[(sr * 6 + j) * 24 + sc * 6 + c] = acc[j][c];
    if (diag) {
#pragma unroll
      for (int j = 0; j < 6; ++j) {
        P[576 + sr * 6 + j] = qq[j];
        P[600 + sc * 6 + j] = kk[j];
      }
    }
  }
}

__global__ __launch_bounds__(640) void dots_reduce(const float* __restrict__ Part,
                                                   float* __restrict__ S) {
  const int bh = blockIdx.x;
  const int job = threadIdx.x;
  if (job >= NJOBS) return;
  float s = 0.f;
  for (int i = 0; i < NSLAB; ++i)
    s += Part[((size_t)bh * NSLAB + i) * NJOBS + job];
  S[bh * NJOBS + job] = s;
}

// ---------------------------------------------------------------------------
// Normalize, softmax, fold proj: M_b = proj_w @ blockdiag(attn_b).
// ---------------------------------------------------------------------------
__global__ __launch_bounds__(576) void build_M(const float* __restrict__ S,
                                               const float* __restrict__ PW,
                                               const float* __restrict__ Temp,
                                               float* __restrict__ M) {
  const int b = blockIdx.x, h = blockIdx.y;
  const int bh = b * 8 + h;
  __shared__ float att[CH][CH];
  __shared__ float qn[CH], kn[CH];
  const int t = threadIdx.x;
  const float* Sb = S + (size_t)bh * NJOBS;

  if (t < CH) {
    qn[t] = fmaxf(sqrtf(Sb[576 + t]), 1e-12f);
    kn[t] = fmaxf(sqrtf(Sb[600 + t]), 1e-12f);
  }
  __syncthreads();
  const float temp = Temp[h];
  if (t < 576) {
    const int c = t / 24, d = t % 24;
    att[c][d] = Sb[t] / (qn[c] * kn[d]) * temp;
  }
  __syncthreads();
  if (t < CH) {
    float mx = -1e30f;
    for (int d = 0; d < CH; ++d) mx = fmaxf(mx, att[t][d]);
    float sum = 0.f;
    for (int d = 0; d < CH; ++d) {
      const float e = __expf(att[t][d] - mx);
      att[t][d] = e;
      sum += e;
    }
    const float inv = 1.f / sum;
    for (int d = 0; d < CH; ++d) att[t][d] *= inv;
  }
  __syncthreads();
  for (int i = t; i < CDIM * CH; i += 576) {
    const int o = i / CH, d = i % CH;
    float s = 0.f;
#pragma unroll
    for (int c = 0; c < CH; ++c) s += PW[o * CDIM + h * CH + c] * att[c][d];
    M[((size_t)b * CDIM + o) * CDIM + h * CH + d] = s;
  }
}

// ---------------------------------------------------------------------------

extern "C" void kernel_launch(void* const* d_in, const int* in_sizes, int n_in,
                              void* d_out, int out_size, void* d_ws, size_t ws_size,
                              hipStream_t stream) {
  const float* x_feat = (const float*)d_in[0];
  const float* y_feat = (const float*)d_in[1];
  const float* q_pw   = (const float*)d_in[2];
  const float* q_dw   = (const float*)d_in[3];
  const float* k_pw   = (const float*)d_in[4];
  const float* k_dw   = (const float*)d_in[5];
  const float* v_pw   = (const float*)d_in[6];
  const float* v_dw   = (const float*)d_in[7];
  const float* proj_w = (const float*)d_in[8];
  const float* temp   = (const float*)d_in[9];
  float* out = (float*)d_out;

  unsigned char* pool;
  (void)hipGetSymbolAddress((void**)&pool, HIP_SYMBOL(g_pool));
  float* t0 = (float*)(pool + OFF_T0);
  float* q  = (float*)(pool + OFF_Q);
  float* k  = (float*)(pool + OFF_K);
  float* v  = (float*)(pool + OFF_V);
  float* part = (float*)(pool + OFF_PART);
  float* S    = (float*)(pool + OFF_S);
  float* M    = (float*)(pool + OFF_M);
  unsigned short* MF = (unsigned short*)(pool + OFF_MF);

  unsigned short* WQF = MF + 2ull * 8 * CDIM * CDIM;
  unsigned short* WKF = WQF + 2ull * CDIM * CDIM;
  unsigned short* WVF = WKF + 2ull * CDIM * CDIM;

  const size_t w1_lo = (size_t)1 * CDIM * CDIM;
  const size_t w8_lo = (size_t)8 * CDIM * CDIM;

  const dim3 ggrid(NPIX / 128, BATCH);   // (128, 8) -> M=192 per block
  const int dwgrid = (NELEM / 4) / 256;

  // weight conversions (tiny)
  w_to_frag<<<12, 64, 0, stream>>>(q_pw, WQF, 1);
  w_to_frag<<<12, 64, 0, stream>>>(k_pw, WKF, 1);
  w_to_frag<<<12, 64, 0, stream>>>(v_pw, WVF, 1);

  // q/k/v = dw(pw(...)), GEMMs read fp32 directly
  mfma_gemm192<<<ggrid, 256, 0, stream>>>(x_feat, WQF, w1_lo, 0, t0);
  dwconv<<<dwgrid, 256, 0, stream>>>(t0, q_dw, q);
  mfma_gemm192<<<ggrid, 256, 0, stream>>>(y_feat, WKF, w1_lo, 0, t0);
  dwconv<<<dwgrid, 256, 0, stream>>>(t0, k_dw, k);
  mfma_gemm192<<<ggrid, 256, 0, stream>>>(y_feat, WVF, w1_lo, 0, t0);
  dwconv<<<dwgrid, 256, 0, stream>>>(t0, v_dw, v);

  // attention gram + softmax + proj fold
  dots_partial<<<dim3(64, NSLAB), 256, 0, stream>>>(q, k, part);
  dots_reduce<<<64, 640, 0, stream>>>(part, S);
  build_M<<<dim3(BATCH, HEADS), 576, 0, stream>>>(S, proj_w, temp, M);
  w_to_frag<<<8 * 12, 64, 0, stream>>>(M, MF, 8);

  // out = M_b @ v (reads fp32 v directly)
  mfma_gemm192<<<ggrid, 256, 0, stream>>>(v, MF, w8_lo, CDIM * CDIM, out);
}